// Round 21
// baseline (308.210 us; speedup 1.0000x reference)
//
#include <hip/hip_runtime.h>
#include <hip/hip_bf16.h>

typedef __bf16 bf16;
typedef __bf16 bf16x8 __attribute__((ext_vector_type(8)));
typedef float f32x4 __attribute__((ext_vector_type(4)));
typedef unsigned char u8;
typedef unsigned int u32;
typedef unsigned short u16;
typedef u16 ushort4v __attribute__((ext_vector_type(4)));

#define B_ 4
#define T_ 1024
#define NX_ 1024
#define NH_ 16
#define HD_ 64

__device__ __forceinline__ void gld16(const void* g, void* l) {
  __builtin_amdgcn_global_load_lds((const __attribute__((address_space(1))) void*)g,
                                   (__attribute__((address_space(3))) void*)l, 16, 0, 0);
}

// ---------- prep: contiguous fp32 -> bf16 ----------
__global__ __launch_bounds__(256) void k_cvt(const float* __restrict__ in, bf16* __restrict__ out, int n) {
  int i = (blockIdx.x * 256 + threadIdx.x) * 4;
  if (i + 3 < n) {
    float4 v = *(const float4*)(in + i);
    out[i] = (bf16)v.x; out[i + 1] = (bf16)v.y; out[i + 2] = (bf16)v.z; out[i + 3] = (bf16)v.w;
  }
}

// ---------- prep: (K,N) f32 -> (N,K) bf16 transpose ----------
__global__ __launch_bounds__(256) void k_transpose(const float* __restrict__ in, bf16* __restrict__ out, int K, int N) {
  __shared__ float tile[64][65];
  int n0 = blockIdx.x * 64, k0 = blockIdx.y * 64;
  for (int i = threadIdx.x; i < 4096; i += 256) {
    int r = i >> 6, c = i & 63;
    tile[r][c] = in[(size_t)(k0 + r) * N + n0 + c];
  }
  __syncthreads();
  for (int i = threadIdx.x; i < 4096; i += 256) {
    int r = i >> 6, c = i & 63;
    out[(size_t)(n0 + r) * K + k0 + c] = (bf16)tile[c][r];
  }
}

// ---------- pack ids into per-(b,tt,st) 1KB tiles: [2][16t][32s] u8 (validated R9 run) ----------
__global__ __launch_bounds__(256) void k_pack(const int* __restrict__ rel, const int* __restrict__ rel_ids,
                                              u8* __restrict__ rib) {
  int tt = blockIdx.x, b = blockIdx.y;
  int tid = threadIdx.x;
  int half = tid >> 7;                       // 0: rel, 1: rel_ids
  int t = (tid & 127) >> 3, g = tid & 7;     // row 0..15, 16B group 0..7
  const int* srcrow = (half ? rel_ids : rel + (size_t)b * T_ * T_) + (size_t)(tt * 16 + t) * T_ + g * 4;
  u8* dst = rib + ((size_t)(b * 64 + tt) * 32) * 1024 + half * 512 + t * 32 + g * 4;
  for (int st = 0; st < 32; ++st) {
    int4 v = *(const int4*)(srcrow + st * 32);
    uchar4 o = {(u8)v.x, (u8)v.y, (u8)v.z, (u8)v.w};
    *(uchar4*)(dst + (size_t)st * 1024) = o;
  }
}

// ---------- rel_values^T as bf16 (64d x 64rr) for epilogue MFMA ----------
__global__ __launch_bounds__(256) void k_rvt(const float* __restrict__ rel_values, bf16* __restrict__ rvT) {
  int d = threadIdx.x >> 2, seg = threadIdx.x & 3;
  for (int i = 0; i < 16; ++i) {
    int rr = seg * 16 + i;
    rvT[d * 64 + rr] = (bf16)rel_values[rr * 64 + d];
  }
}

// ---------- 128x128 bf16 MFMA GEMM; EPI 0 writes per-(bh,st) swizzled K/V tiles (validated R9) ----------
template <int EPI>
__global__ __launch_bounds__(256) void k_gemm(
    const bf16* __restrict__ A, const bf16* __restrict__ BT, const float* __restrict__ bias,
    float* __restrict__ outF, bf16* __restrict__ qg, bf16* __restrict__ kg, bf16* __restrict__ vtg,
    int M, int N, int K) {
  __shared__ __align__(16) bf16 Ab[2][128 * 32];
  __shared__ __align__(16) bf16 Bb[2][128 * 32];
  int tid = threadIdx.x, lane = tid & 63, w = tid >> 6;
  int wm = w >> 1, wn = w & 1;
  int m0 = blockIdx.y * 128, n0 = blockIdx.x * 128;
  int sl = lane >> 4, lr = lane & 15;
  f32x4 acc[4][4] = {};
  int NKt = K >> 5;

  auto stage = [&](int kt, int bidx) {
    const bf16* Ag = A + (size_t)m0 * K + kt * 32;
    const bf16* Bg = BT + (size_t)n0 * K + kt * 32;
#pragma unroll
    for (int j = 0; j < 2; ++j) {
      int c = w * 128 + j * 64 + lane;
      int row = c >> 2, slot = c & 3;
      int ss = slot ^ ((row >> 1) & 3);
      gld16(Ag + (size_t)row * K + ss * 8, &Ab[bidx][(w * 128 + j * 64) * 8]);
      gld16(Bg + (size_t)row * K + ss * 8, &Bb[bidx][(w * 128 + j * 64) * 8]);
    }
  };
  stage(0, 0);
  for (int kt = 0; kt < NKt; ++kt) {
    int bidx = kt & 1;
    __syncthreads();
    if (kt + 1 < NKt) stage(kt + 1, bidx ^ 1);
    bf16x8 af[4], bfv[4];
#pragma unroll
    for (int mi = 0; mi < 4; ++mi) {
      int row = wm * 64 + mi * 16 + lr;
      af[mi] = *(const bf16x8*)&Ab[bidx][row * 32 + ((sl ^ ((row >> 1) & 3)) * 8)];
    }
#pragma unroll
    for (int ni = 0; ni < 4; ++ni) {
      int row = wn * 64 + ni * 16 + lr;
      bfv[ni] = *(const bf16x8*)&Bb[bidx][row * 32 + ((sl ^ ((row >> 1) & 3)) * 8)];
    }
#pragma unroll
    for (int mi = 0; mi < 4; ++mi)
#pragma unroll
      for (int ni = 0; ni < 4; ++ni)
        acc[mi][ni] = __builtin_amdgcn_mfma_f32_16x16x32_bf16(af[mi], bfv[ni], acc[mi][ni], 0, 0, 0);
  }
#pragma unroll
  for (int ni = 0; ni < 4; ++ni) {
    int n = n0 + wn * 64 + ni * 16 + lr;
    float bv = bias[n];
#pragma unroll
    for (int mi = 0; mi < 4; ++mi) {
      int mb = m0 + wm * 64 + mi * 16 + sl * 4;
#pragma unroll
      for (int r = 0; r < 4; ++r) {
        float v = acc[mi][ni][r] + bv;
        int m = mb + r;
        if (EPI == 0) {
          int region = n >> 10, hh = (n & 1023) >> 6, d = n & 63;
          int bb = m >> 10, t = m & 1023;
          int bh = bb * NH_ + hh;
          int st = t >> 5, s = t & 31;
          if (region == 0) {
            qg[((size_t)bh * T_ + t) * HD_ + d] = (bf16)v;
          } else if (region == 1) {
            // K tile [32s][64d], d-slot(8x8el) swizzled by s&7
            int dpos = (d & 7) | ((((d >> 3) ^ (s & 7)) & 7) << 3);
            kg[((size_t)(bh * 32 + st) * 32 + s) * 64 + dpos] = (bf16)v;
          } else {
            // V tile [64d][32s], s-slot(4x8el) swizzled by (d>>1)&3
            int spos = (s & 7) | ((((s >> 3) ^ ((d >> 1) & 3)) & 3) << 3);
            vtg[((size_t)(bh * 32 + st) * 64 + d) * 32 + spos] = (bf16)v;
          }
        } else {
          outF[(size_t)m * N + n] = v;
        }
      }
    }
  }
}

// ---------- K/V-shared fused attention: 1 block = (b,h) x 4 strip-pairs (8 strips) ----------
// K/V staged to LDS once per block per s-tile (4 waves share); each wave owns 2 strips fully.
// Reduces K/V re-read 32x -> 6.25x. m97-style barrier double-buffer.

#define STRIP_COMPUTE(IDP, QF0, QF1, ACC, LSUM, PRELP, TG, S0V)                   \
  do {                                                                            \
    int s0_ = (S0V);                                                              \
    f32x4 S0_ = {}, S1_ = {};                                                     \
    {                                                                             \
      bf16x8 ka00 = *(const bf16x8*)&KBc[lr * 64 + (((0 + sl) ^ (lr & 7)) * 8)];  \
      bf16x8 ka01 = *(const bf16x8*)&KBc[lr * 64 + (((4 + sl) ^ (lr & 7)) * 8)];  \
      bf16x8 ka10 = *(const bf16x8*)&KBc[(16 + lr) * 64 + (((0 + sl) ^ (lr & 7)) * 8)]; \
      bf16x8 ka11 = *(const bf16x8*)&KBc[(16 + lr) * 64 + (((4 + sl) ^ (lr & 7)) * 8)]; \
      S0_ = __builtin_amdgcn_mfma_f32_16x16x32_bf16(ka00, QF0, S0_, 0, 0, 0);     \
      S0_ = __builtin_amdgcn_mfma_f32_16x16x32_bf16(ka01, QF1, S0_, 0, 0, 0);     \
      S1_ = __builtin_amdgcn_mfma_f32_16x16x32_bf16(ka10, QF0, S1_, 0, 0, 0);     \
      S1_ = __builtin_amdgcn_mfma_f32_16x16x32_bf16(ka11, QF1, S1_, 0, 0, 0);     \
    }                                                                             \
    u32 rid0 = *(const u32*)&(IDP)[lr * 32 + sl * 4];                             \
    u32 rid1 = *(const u32*)&(IDP)[lr * 32 + 16 + sl * 4];                        \
    u32 iid0 = *(const u32*)&(IDP)[512 + lr * 32 + sl * 4];                       \
    u32 iid1 = *(const u32*)&(IDP)[512 + lr * 32 + 16 + sl * 4];                  \
    u16 pb_[8];                                                                   \
    {                                                                             \
      int sbase_ = s0_ + sl * 4;                                                  \
      _Pragma("unroll") for (int r = 0; r < 4; ++r) {                             \
        float e = (sbase_ + r <= (TG))                                            \
                      ? __expf(S0_[r] * 0.125f) * tab[(rid0 >> (8 * r)) & 63]     \
                      : 0.f;                                                      \
        LSUM += e;                                                                \
        bf16 eb = (bf16)e;                                                        \
        pb_[r] = *(u16*)&eb;                                                      \
        if (e != 0.f) atomicAdd(&(PRELP)[lr * 68 + ((iid0 >> (8 * r)) & 63)], e); \
      }                                                                           \
      sbase_ += 16;                                                               \
      _Pragma("unroll") for (int r = 0; r < 4; ++r) {                             \
        float e = (sbase_ + r <= (TG))                                            \
                      ? __expf(S1_[r] * 0.125f) * tab[(rid1 >> (8 * r)) & 63]     \
                      : 0.f;                                                      \
        LSUM += e;                                                                \
        bf16 eb = (bf16)e;                                                        \
        pb_[4 + r] = *(u16*)&eb;                                                  \
        if (e != 0.f) atomicAdd(&(PRELP)[lr * 68 + ((iid1 >> (8 * r)) & 63)], e); \
      }                                                                           \
    }                                                                             \
    u32 a0_ = (u32)pb_[0] | ((u32)pb_[1] << 16);                                  \
    u32 b0_ = (u32)pb_[2] | ((u32)pb_[3] << 16);                                  \
    u32 a1_ = (u32)pb_[4] | ((u32)pb_[5] << 16);                                  \
    u32 b1_ = (u32)pb_[6] | ((u32)pb_[7] << 16);                                  \
    int srcA_ = lr + (((sl & 1) * 2) << 4);                                       \
    int srcB_ = srcA_ + 16;                                                       \
    u32 taA0_ = (u32)__shfl((int)a0_, srcA_), taA1_ = (u32)__shfl((int)a1_, srcA_); \
    u32 tbA0_ = (u32)__shfl((int)b0_, srcA_), tbA1_ = (u32)__shfl((int)b1_, srcA_); \
    u32 taB0_ = (u32)__shfl((int)a0_, srcB_), taB1_ = (u32)__shfl((int)a1_, srcB_); \
    u32 tbB0_ = (u32)__shfl((int)b0_, srcB_), tbB1_ = (u32)__shfl((int)b1_, srcB_); \
    bool hi_ = (sl & 2) != 0;                                                     \
    u32 wv0_ = hi_ ? taA1_ : taA0_;                                               \
    u32 wv1_ = hi_ ? tbA1_ : tbA0_;                                               \
    u32 wv2_ = hi_ ? taB1_ : taB0_;                                               \
    u32 wv3_ = hi_ ? tbB1_ : tbB0_;                                               \
    u16 pfw_[8];                                                                  \
    *(u32*)&pfw_[0] = wv0_; *(u32*)&pfw_[2] = wv1_;                               \
    *(u32*)&pfw_[4] = wv2_; *(u32*)&pfw_[6] = wv3_;                               \
    bf16x8 pfrag_ = *(bf16x8*)&pfw_[0];                                           \
    _Pragma("unroll") for (int ni = 0; ni < 4; ++ni) {                            \
      int d_ = ni * 16 + lr;                                                      \
      bf16x8 vb_ = *(const bf16x8*)&VBc[d_ * 32 + ((sl ^ ((lr >> 1) & 3)) * 8)];  \
      ACC[ni] = __builtin_amdgcn_mfma_f32_16x16x32_bf16(vb_, pfrag_, ACC[ni], 0, 0, 0); \
    }                                                                             \
  } while (0)

#define STRIP_EPI(T0V, ACC, LSUM, PRELP)                                          \
  do {                                                                            \
    int t0_ = (T0V);                                                              \
    float ls_ = (LSUM);                                                           \
    ls_ += __shfl_xor(ls_, 16);                                                   \
    ls_ += __shfl_xor(ls_, 32);                                                   \
    float inv_ = 1.f / ls_;                                                       \
    _Pragma("unroll") for (int kc = 0; kc < 2; ++kc) {                            \
      f32x4 pA_ = *(const f32x4*)&(PRELP)[lr * 68 + kc * 32 + sl * 8];            \
      f32x4 pB_ = *(const f32x4*)&(PRELP)[lr * 68 + kc * 32 + sl * 8 + 4];        \
      u16 pb_[8];                                                                 \
      _Pragma("unroll") for (int jj = 0; jj < 4; ++jj) { bf16 xx = (bf16)pA_[jj]; pb_[jj] = *(u16*)&xx; } \
      _Pragma("unroll") for (int jj = 0; jj < 4; ++jj) { bf16 xx = (bf16)pB_[jj]; pb_[4 + jj] = *(u16*)&xx; } \
      bf16x8 pfrag_ = *(bf16x8*)&pb_[0];                                          \
      _Pragma("unroll") for (int ni = 0; ni < 4; ++ni) {                          \
        bf16x8 af_ = *(const bf16x8*)(rvT + (size_t)(ni * 16 + lr) * 64 + kc * 32 + sl * 8); \
        ACC[ni] = __builtin_amdgcn_mfma_f32_16x16x32_bf16(af_, pfrag_, ACC[ni], 0, 0, 0); \
      }                                                                           \
    }                                                                             \
    bf16* rp_ = ret + ((size_t)(b * T_ + t0_ + lr)) * NX_ + h * HD_ + sl * 4;     \
    _Pragma("unroll") for (int ni = 0; ni < 4; ++ni) {                            \
      ushort4v ov_;                                                               \
      _Pragma("unroll") for (int r = 0; r < 4; ++r) {                             \
        bf16 xx = (bf16)(ACC[ni][r] * inv_);                                      \
        ov_[r] = *(u16*)&xx;                                                      \
      }                                                                           \
      *(ushort4v*)(rp_ + ni * 16) = ov_;                                          \
    }                                                                             \
  } while (0)

#define STAGE(ST, BIDX)                                                           \
  do {                                                                            \
    int st_ = (ST);                                                               \
    gld16(ktile + (size_t)st_ * 2048, &KB[BIDX][w * 512]);                        \
    gld16(vtile + (size_t)st_ * 2048, &VB[BIDX][w * 512]);                        \
    if (st_ <= hmax) gld16(ribH + (size_t)st_ * 1024, &IDT[BIDX][w][0][0]);       \
    if (st_ <= lmax) gld16(ribL + (size_t)st_ * 1024, &IDT[BIDX][w][1][0]);       \
  } while (0)

__global__ __launch_bounds__(256, 2) void k_attn(
    const bf16* __restrict__ qg, const bf16* __restrict__ kg, const bf16* __restrict__ vtg,
    const u8* __restrict__ rib, const float* __restrict__ rel_weights,
    const bf16* __restrict__ rvT, bf16* __restrict__ ret) {
  __shared__ __align__(16) bf16 KB[2][2048];     // K tile [32s][64d], pre-swizzled
  __shared__ __align__(16) bf16 VB[2][2048];     // V^T tile [64d][32s], pre-swizzled
  __shared__ __align__(16) u8 IDT[2][4][2][1024]; // [buf][wave][h/l] id tiles
  __shared__ float prelB[8][1088];               // per (wave,side) buckets [16t][64+4]
  __shared__ float tab[64];

  int bid = blockIdx.x;
  int x = bid & 7, j = bid >> 3;                 // XCD-chunked: (b,h) group per XCD
  int b = x >> 1;
  int h = (x & 1) + ((j >> 3) << 1);
  int q = j & 7;
  int w = threadIdx.x >> 6;
  int lane = threadIdx.x & 63;
  int lr = lane & 15, sl = lane >> 4;
  int bh = b * NH_ + h;

  int th = 63 - 4 * q - w;                       // heavy strip (owned by this wave)
  int tl = 4 * q + w;                            // light strip
  int hmax = th >> 1, lmax = tl >> 1;            // last s-tile each strip needs
  int nst = 32 - 2 * q;                          // block tile-loop bound (= hmax(w=0)+1)

  if (threadIdx.x < 64) tab[threadIdx.x] = __expf(rel_weights[threadIdx.x * NH_ + h]);
  for (int i = threadIdx.x; i < 8 * 1088; i += 256) ((float*)prelB)[i] = 0.f;

  // Q B-frags for both strips (lane: t=lr, k-chunk=sl)
  const bf16* qH = qg + ((size_t)bh * T_ + th * 16 + lr) * HD_;
  const bf16* qL = qg + ((size_t)bh * T_ + tl * 16 + lr) * HD_;
  bf16x8 qH0 = *(const bf16x8*)(qH + sl * 8);
  bf16x8 qH1 = *(const bf16x8*)(qH + 32 + sl * 8);
  bf16x8 qL0 = *(const bf16x8*)(qL + sl * 8);
  bf16x8 qL1 = *(const bf16x8*)(qL + 32 + sl * 8);

  int tgH = th * 16 + lr, tgL = tl * 16 + lr;
  float* prelH = &prelB[w * 2 + 0][0];
  float* prelL = &prelB[w * 2 + 1][0];
  const u8* ribH = rib + ((size_t)(b * 64 + th) * 32) * 1024 + lane * 16;
  const u8* ribL = rib + ((size_t)(b * 64 + tl) * 32) * 1024 + lane * 16;
  const bf16* ktile = kg + (size_t)bh * 32 * 2048 + w * 512 + lane * 8;
  const bf16* vtile = vtg + (size_t)bh * 32 * 2048 + w * 512 + lane * 8;

  f32x4 accH[4] = {}, accL[4] = {};
  float lsumH = 0.f, lsumL = 0.f;

  STAGE(0, 0);
  for (int st = 0; st < nst; ++st) {
    int bidx = st & 1;
    __syncthreads();                             // buf ready (vmcnt drained), prev reads done
    if (st + 1 < nst) STAGE(st + 1, bidx ^ 1);   // next tile flies under this tile's compute
    const bf16* KBc = &KB[bidx][0];
    const bf16* VBc = &VB[bidx][0];
    if (st <= hmax)
      STRIP_COMPUTE((&IDT[bidx][w][0][0]), qH0, qH1, accH, lsumH, prelH, tgH, st * 32);
    if (st <= lmax)
      STRIP_COMPUTE((&IDT[bidx][w][1][0]), qL0, qL1, accL, lsumL, prelL, tgL, st * 32);
  }

  // per-wave epilogues (own prel/acc; no cross-wave sync needed)
  STRIP_EPI(th * 16, accH, lsumH, prelH);
  STRIP_EPI(tl * 16, accL, lsumL, prelL);
}

extern "C" void kernel_launch(void* const* d_in, const int* in_sizes, int n_in,
                              void* d_out, int out_size, void* d_ws, size_t ws_size,
                              hipStream_t stream) {
  const float* x = (const float*)d_in[0];
  const int* rel = (const int*)d_in[1];
  const float* w_attn = (const float*)d_in[2];
  const float* b_attn = (const float*)d_in[3];
  const float* w_proj = (const float*)d_in[4];
  const float* b_proj = (const float*)d_in[5];
  const float* rel_weights = (const float*)d_in[6];
  const float* rel_values = (const float*)d_in[7];
  const int* rel_ids = (const int*)d_in[8];
  float* out = (float*)d_out;

  char* ws = (char*)d_ws;
  bf16* xb  = (bf16*)(ws);                    //  8 MB: x as bf16 (consumed by gemm<0>)
  bf16* wTa = (bf16*)(ws + 8388608);          //  6 MB: w_attn^T
  bf16* wTp = (bf16*)(ws + 14680064);         //  2 MB: w_proj^T
  bf16* qg  = (bf16*)(ws + 16777216);         //  8 MB: q rows (bh,t,d)
  bf16* kg  = (bf16*)(ws + 25165824);         //  8 MB: K tiles (bh,st,32s,64d) swizzled
  bf16* vtg = (bf16*)(ws + 33554432);         //  8 MB: V tiles (bh,st,64d,32s) swizzled
  bf16* ret = (bf16*)(ws + 41943040);         //  8 MB: attn out (b,t,nx)
  u8* rib   = (u8*)(ws);                      //  8 MB: id tiles (b,tt,st,2,16,32), overlays dead xb
  bf16* rvT = (bf16*)(ws + 14680064 + 2097152 - 16384);  // 8 KB at tail of wTp region (wTp is 2MB, rvT uses last 16KB-8KB... placed after wTp use)

  // place rvT safely in its own slot after ret
  rvT = (bf16*)(ws + 49283072 + 1048576);     // past ret (41943040+8388608=50331648? keep simple below)
  rvT = (bf16*)(ws + 50331648);               // 8 KB after all other regions

  k_cvt<<<4096, 256, 0, stream>>>(x, xb, 4194304);
  k_transpose<<<dim3(48, 16), 256, 0, stream>>>(w_attn, wTa, 1024, 3072);
  k_transpose<<<dim3(16, 16), 256, 0, stream>>>(w_proj, wTp, 1024, 1024);
  k_gemm<0><<<dim3(24, 32), 256, 0, stream>>>(xb, wTa, b_attn, nullptr, qg, kg, vtg, 4096, 3072, 1024);
  k_pack<<<dim3(64, 4), 256, 0, stream>>>(rel, rel_ids, rib);
  k_rvt<<<1, 256, 0, stream>>>(rel_values, rvT);
  k_attn<<<512, 256, 0, stream>>>(qg, kg, vtg, rib, rel_weights, rvT, ret);
  k_gemm<1><<<dim3(8, 32), 256, 0, stream>>>(ret, wTp, b_proj, out, nullptr, nullptr, nullptr, 4096, 1024, 1024);
}

// Round 23
// 281.537 us; speedup vs baseline: 1.0947x; 1.0947x over previous
//
#include <hip/hip_runtime.h>
#include <hip/hip_bf16.h>

typedef __bf16 bf16;
typedef __bf16 bf16x8 __attribute__((ext_vector_type(8)));
typedef float f32x4 __attribute__((ext_vector_type(4)));
typedef unsigned char u8;
typedef unsigned int u32;
typedef unsigned short u16;
typedef u16 ushort4v __attribute__((ext_vector_type(4)));
typedef u32 u32x4 __attribute__((ext_vector_type(4)));

#define B_ 4
#define T_ 1024
#define NX_ 1024
#define NH_ 16
#define HD_ 64

__device__ __forceinline__ void gld16(const void* g, void* l) {
  __builtin_amdgcn_global_load_lds((const __attribute__((address_space(1))) void*)g,
                                   (__attribute__((address_space(3))) void*)l, 16, 0, 0);
}

// ---------- prep: contiguous fp32 -> bf16 ----------
__global__ __launch_bounds__(256) void k_cvt(const float* __restrict__ in, bf16* __restrict__ out, int n) {
  int i = (blockIdx.x * 256 + threadIdx.x) * 4;
  if (i + 3 < n) {
    float4 v = *(const float4*)(in + i);
    out[i] = (bf16)v.x; out[i + 1] = (bf16)v.y; out[i + 2] = (bf16)v.z; out[i + 3] = (bf16)v.w;
  }
}

// ---------- prep: (K,N) f32 -> (N,K) bf16 transpose ----------
__global__ __launch_bounds__(256) void k_transpose(const float* __restrict__ in, bf16* __restrict__ out, int K, int N) {
  __shared__ float tile[64][65];
  int n0 = blockIdx.x * 64, k0 = blockIdx.y * 64;
  for (int i = threadIdx.x; i < 4096; i += 256) {
    int r = i >> 6, c = i & 63;
    tile[r][c] = in[(size_t)(k0 + r) * N + n0 + c];
  }
  __syncthreads();
  for (int i = threadIdx.x; i < 4096; i += 256) {
    int r = i >> 6, c = i & 63;
    out[(size_t)(n0 + r) * K + k0 + c] = (bf16)tile[c][r];
  }
}

// ---------- pack int32 ids -> u8 ([t][s] natural layout; rel 4MB then rel_ids 1MB) ----------
__global__ __launch_bounds__(256) void k_pack(const int* __restrict__ rel, const int* __restrict__ rel_ids,
                                              u8* __restrict__ dst8) {
  int i = (blockIdx.x * 256 + threadIdx.x) * 4;
  const int* src = (i < 4194304) ? (rel + i) : (rel_ids + (i - 4194304));
  int4 v = *(const int4*)src;
  uchar4 o = {(u8)v.x, (u8)v.y, (u8)v.z, (u8)v.w};
  *(uchar4*)(dst8 + i) = o;
}

// ---------- rel_values^T as bf16 (64d x 64rr) for epilogue MFMA ----------
__global__ __launch_bounds__(256) void k_rvt(const float* __restrict__ rel_values, bf16* __restrict__ rvT) {
  int d = threadIdx.x >> 2, seg = threadIdx.x & 3;
  for (int i = 0; i < 16; ++i) {
    int rr = seg * 16 + i;
    rvT[d * 64 + rr] = (bf16)rel_values[rr * 64 + d];
  }
}

// ---------- 128x128 bf16 MFMA GEMM, BK=32, double-buffered global_load_lds ----------
template <int EPI>
__global__ __launch_bounds__(256) void k_gemm(
    const bf16* __restrict__ A, const bf16* __restrict__ BT, const float* __restrict__ bias,
    float* __restrict__ outF, bf16* __restrict__ qg, bf16* __restrict__ kg, bf16* __restrict__ vtg,
    int M, int N, int K) {
  __shared__ __align__(16) bf16 Ab[2][128 * 32];
  __shared__ __align__(16) bf16 Bb[2][128 * 32];
  int tid = threadIdx.x, lane = tid & 63, w = tid >> 6;
  int wm = w >> 1, wn = w & 1;
  int m0 = blockIdx.y * 128, n0 = blockIdx.x * 128;
  int sl = lane >> 4, lr = lane & 15;
  f32x4 acc[4][4] = {};
  int NKt = K >> 5;

  auto stage = [&](int kt, int bidx) {
    const bf16* Ag = A + (size_t)m0 * K + kt * 32;
    const bf16* Bg = BT + (size_t)n0 * K + kt * 32;
#pragma unroll
    for (int j = 0; j < 2; ++j) {
      int c = w * 128 + j * 64 + lane;
      int row = c >> 2, slot = c & 3;
      int ss = slot ^ ((row >> 1) & 3);
      gld16(Ag + (size_t)row * K + ss * 8, &Ab[bidx][(w * 128 + j * 64) * 8]);
      gld16(Bg + (size_t)row * K + ss * 8, &Bb[bidx][(w * 128 + j * 64) * 8]);
    }
  };
  stage(0, 0);
  for (int kt = 0; kt < NKt; ++kt) {
    int bidx = kt & 1;
    __syncthreads();
    if (kt + 1 < NKt) stage(kt + 1, bidx ^ 1);
    bf16x8 af[4], bfv[4];
#pragma unroll
    for (int mi = 0; mi < 4; ++mi) {
      int row = wm * 64 + mi * 16 + lr;
      af[mi] = *(const bf16x8*)&Ab[bidx][row * 32 + ((sl ^ ((row >> 1) & 3)) * 8)];
    }
#pragma unroll
    for (int ni = 0; ni < 4; ++ni) {
      int row = wn * 64 + ni * 16 + lr;
      bfv[ni] = *(const bf16x8*)&Bb[bidx][row * 32 + ((sl ^ ((row >> 1) & 3)) * 8)];
    }
#pragma unroll
    for (int mi = 0; mi < 4; ++mi)
#pragma unroll
      for (int ni = 0; ni < 4; ++ni)
        acc[mi][ni] = __builtin_amdgcn_mfma_f32_16x16x32_bf16(af[mi], bfv[ni], acc[mi][ni], 0, 0, 0);
  }
#pragma unroll
  for (int ni = 0; ni < 4; ++ni) {
    int n = n0 + wn * 64 + ni * 16 + lr;
    float bv = bias[n];
#pragma unroll
    for (int mi = 0; mi < 4; ++mi) {
      int mb = m0 + wm * 64 + mi * 16 + sl * 4;
#pragma unroll
      for (int r = 0; r < 4; ++r) {
        float v = acc[mi][ni][r] + bv;
        int m = mb + r;
        if (EPI == 0) {
          int region = n >> 10, hh = (n & 1023) >> 6, d = n & 63;
          int bb = m >> 10, t = m & 1023;
          int bh = bb * NH_ + hh;
          if (region == 0)      qg[((size_t)bh * T_ + t) * HD_ + d] = (bf16)v;
          else if (region == 1) kg[((size_t)bh * T_ + t) * HD_ + d] = (bf16)v;
          else                  vtg[((size_t)bh * HD_ + d) * T_ + t] = (bf16)v;
        } else {
          outF[(size_t)m * N + n] = v;
        }
      }
    }
  }
}

// ---------- wave-paired fused attention; 64-wide s-tiles (halved iteration count) ----------
// Same validated R16 structure (pairing, XCD remap, asm loads, counted vmcnt), tile width 2x.
// Ping-pong registers referenced via token-pasted prefix (a/b) to avoid macro-arg expansion.

#define GLD4(dst, ptr) asm volatile("global_load_dwordx4 %0, %1, off" : "=v"(dst) : "v"(ptr))
#define GLD1(dst, ptr) asm volatile("global_load_dword %0, %1, off" : "=v"(dst) : "v"(ptr))

#define LOADKV64(s0v, P)                                                         \
  do {                                                                           \
    int s0_ = (s0v);                                                             \
    GLD4(P##k0, klane + (size_t)s0_ * HD_);                                      \
    GLD4(P##k1, klane + (size_t)s0_ * HD_ + 32);                                 \
    GLD4(P##k2, klane + (size_t)(s0_ + 16) * HD_);                               \
    GLD4(P##k3, klane + (size_t)(s0_ + 16) * HD_ + 32);                          \
    GLD4(P##k4, klane + (size_t)(s0_ + 32) * HD_);                               \
    GLD4(P##k5, klane + (size_t)(s0_ + 32) * HD_ + 32);                          \
    GLD4(P##k6, klane + (size_t)(s0_ + 48) * HD_);                               \
    GLD4(P##k7, klane + (size_t)(s0_ + 48) * HD_ + 32);                          \
    GLD4(P##va0, vlane + s0_);                                                   \
    GLD4(P##va1, vlane + 16 * T_ + s0_);                                         \
    GLD4(P##va2, vlane + 32 * T_ + s0_);                                         \
    GLD4(P##va3, vlane + 48 * T_ + s0_);                                         \
    GLD4(P##vb0, vlane + s0_ + 32);                                              \
    GLD4(P##vb1, vlane + 16 * T_ + s0_ + 32);                                    \
    GLD4(P##vb2, vlane + 32 * T_ + s0_ + 32);                                    \
    GLD4(P##vb3, vlane + 48 * T_ + s0_ + 32);                                    \
    GLD1(P##r0, ridlane + s0_);                                                  \
    GLD1(P##r1, ridlane + s0_ + 16);                                             \
    GLD1(P##r2, ridlane + s0_ + 32);                                             \
    GLD1(P##r3, ridlane + s0_ + 48);                                             \
    GLD1(P##i0, iidlane + s0_);                                                  \
    GLD1(P##i1, iidlane + s0_ + 16);                                             \
    GLD1(P##i2, iidlane + s0_ + 32);                                             \
    GLD1(P##i3, iidlane + s0_ + 48);                                             \
  } while (0)

// one si sub-block: S MFMA pair -> softmax -> pack 2 dwords + bucket atomics
#define SM_SI(SI, KA, KB2, RID, IID, AOUT, BOUT)                                 \
  do {                                                                           \
    f32x4 S_ = {};                                                               \
    S_ = __builtin_amdgcn_mfma_f32_16x16x32_bf16(__builtin_bit_cast(bf16x8, KA), qf0_, S_, 0, 0, 0); \
    S_ = __builtin_amdgcn_mfma_f32_16x16x32_bf16(__builtin_bit_cast(bf16x8, KB2), qf1_, S_, 0, 0, 0); \
    u16 p_[4];                                                                   \
    int sb_ = s0_ + (SI) * 16 + sl * 4;                                          \
    _Pragma("unroll") for (int r = 0; r < 4; ++r) {                              \
      float e = (sb_ + r <= tglob)                                               \
                    ? __expf(S_[r] * 0.125f) * tab[((RID) >> (8 * r)) & 63]      \
                    : 0.f;                                                       \
      lsum += e;                                                                 \
      bf16 eb = (bf16)e;                                                         \
      p_[r] = *(u16*)&eb;                                                        \
      if (e != 0.f) atomicAdd(&prel[lr * 68 + (((IID) >> (8 * r)) & 63)], e);    \
    }                                                                            \
    AOUT = (u32)p_[0] | ((u32)p_[1] << 16);                                      \
    BOUT = (u32)p_[2] | ((u32)p_[3] << 16);                                      \
  } while (0)

// build one P-fragment (32 s-values) from two si dword pairs via shuffles
#define PFRAG(A0, B0, A1, B1, OUT)                                               \
  do {                                                                           \
    u32 taA0_ = (u32)__shfl((int)(A0), srcA_), taA1_ = (u32)__shfl((int)(A1), srcA_); \
    u32 tbA0_ = (u32)__shfl((int)(B0), srcA_), tbA1_ = (u32)__shfl((int)(B1), srcA_); \
    u32 taB0_ = (u32)__shfl((int)(A0), srcB_), taB1_ = (u32)__shfl((int)(A1), srcB_); \
    u32 tbB0_ = (u32)__shfl((int)(B0), srcB_), tbB1_ = (u32)__shfl((int)(B1), srcB_); \
    u16 pw_[8];                                                                  \
    *(u32*)&pw_[0] = hi_ ? taA1_ : taA0_;                                        \
    *(u32*)&pw_[2] = hi_ ? tbA1_ : tbA0_;                                        \
    *(u32*)&pw_[4] = hi_ ? taB1_ : taB0_;                                        \
    *(u32*)&pw_[6] = hi_ ? tbB1_ : tbB0_;                                        \
    OUT = *(bf16x8*)&pw_[0];                                                     \
  } while (0)

#define COMPUTE64(s0v, P)                                                        \
  do {                                                                           \
    int s0_ = (s0v);                                                             \
    bf16x8 qf0_ = __builtin_bit_cast(bf16x8, qr0);                               \
    bf16x8 qf1_ = __builtin_bit_cast(bf16x8, qr1);                               \
    u32 a0_, b0_, a1_, b1_, a2_, b2_, a3_, b3_;                                  \
    SM_SI(0, P##k0, P##k1, P##r0, P##i0, a0_, b0_);                              \
    SM_SI(1, P##k2, P##k3, P##r1, P##i1, a1_, b1_);                              \
    SM_SI(2, P##k4, P##k5, P##r2, P##i2, a2_, b2_);                              \
    SM_SI(3, P##k6, P##k7, P##r3, P##i3, a3_, b3_);                              \
    int srcA_ = lr + (((sl & 1) * 2) << 4);                                      \
    int srcB_ = srcA_ + 16;                                                      \
    bool hi_ = (sl & 2) != 0;                                                    \
    bf16x8 pfA_, pfB_;                                                           \
    PFRAG(a0_, b0_, a1_, b1_, pfA_);                                             \
    PFRAG(a2_, b2_, a3_, b3_, pfB_);                                             \
    acc[0] = __builtin_amdgcn_mfma_f32_16x16x32_bf16(__builtin_bit_cast(bf16x8, P##va0), pfA_, acc[0], 0, 0, 0); \
    acc[1] = __builtin_amdgcn_mfma_f32_16x16x32_bf16(__builtin_bit_cast(bf16x8, P##va1), pfA_, acc[1], 0, 0, 0); \
    acc[2] = __builtin_amdgcn_mfma_f32_16x16x32_bf16(__builtin_bit_cast(bf16x8, P##va2), pfA_, acc[2], 0, 0, 0); \
    acc[3] = __builtin_amdgcn_mfma_f32_16x16x32_bf16(__builtin_bit_cast(bf16x8, P##va3), pfA_, acc[3], 0, 0, 0); \
    acc[0] = __builtin_amdgcn_mfma_f32_16x16x32_bf16(__builtin_bit_cast(bf16x8, P##vb0), pfB_, acc[0], 0, 0, 0); \
    acc[1] = __builtin_amdgcn_mfma_f32_16x16x32_bf16(__builtin_bit_cast(bf16x8, P##vb1), pfB_, acc[1], 0, 0, 0); \
    acc[2] = __builtin_amdgcn_mfma_f32_16x16x32_bf16(__builtin_bit_cast(bf16x8, P##vb2), pfB_, acc[2], 0, 0, 0); \
    acc[3] = __builtin_amdgcn_mfma_f32_16x16x32_bf16(__builtin_bit_cast(bf16x8, P##vb3), pfB_, acc[3], 0, 0, 0); \
  } while (0)

#define WAIT24() do { asm volatile("s_waitcnt vmcnt(24)" ::: "memory"); __builtin_amdgcn_sched_barrier(0); } while (0)
#define WAIT0()  do { asm volatile("s_waitcnt vmcnt(0)"  ::: "memory"); __builtin_amdgcn_sched_barrier(0); } while (0)

__global__ __launch_bounds__(256, 2) void k_attn(
    const bf16* __restrict__ qg, const bf16* __restrict__ kg, const bf16* __restrict__ vtg,
    const u8* __restrict__ rel8, const float* __restrict__ rel_weights,
    const u8* __restrict__ relid8, const bf16* __restrict__ rvT,
    bf16* __restrict__ ret) {
  __shared__ float prelBase[4 * 1088];   // per-wave [16t][64+4pad]
  __shared__ float tabBase[4 * 64];      // per-wave exp(rel_weights[:,h])

  int bid = blockIdx.x;
  int x = bid & 7, j = bid >> 3;
  int b = x >> 1;
  int h = (x & 1) + ((j >> 3) << 1);
  int q = j & 7;
  int w = threadIdx.x >> 6;
  int lane = threadIdx.x & 63;
  int lr = lane & 15, sl = lane >> 4;
  int p = q * 4 + w;                     // pair index in [0,32)
  int bh = b * NH_ + h;

  float* prel = prelBase + w * 1088;
  float* tab = tabBase + w * 64;
  tab[lane] = __expf(rel_weights[lane * NH_ + h]);

  const u8* relbase = rel8 + (size_t)b * T_ * T_;

#pragma unroll
  for (int side = 0; side < 2; ++side) {
    int tt = side ? p : 63 - p;          // heavy strip first
    int t0 = tt * 16;
    int tglob = t0 + lr;

#pragma unroll
    for (int i = 0; i < 17; ++i) prel[i * 64 + lane] = 0.f;

    const bf16* qrow = qg + ((size_t)bh * T_ + t0 + lr) * HD_;
    const bf16* klane = kg + ((size_t)bh * T_ + lr) * HD_ + sl * 8;
    const bf16* vlane = vtg + ((size_t)bh * HD_ + lr) * T_ + sl * 8;
    const u8* ridlane = relbase + (size_t)(t0 + lr) * T_ + sl * 4;
    const u8* iidlane = relid8 + (size_t)(t0 + lr) * T_ + sl * 4;

    f32x4 acc[4] = {};
    float lsum = 0.f;

    u32x4 qr0, qr1;
    GLD4(qr0, qrow + sl * 8);
    GLD4(qr1, qrow + 32 + sl * 8);

    u32x4 ak0, ak1, ak2, ak3, ak4, ak5, ak6, ak7, ava0, ava1, ava2, ava3, avb0, avb1, avb2, avb3;
    u32 ar0, ar1, ar2, ar3, ai0, ai1, ai2, ai3;
    u32x4 bk0, bk1, bk2, bk3, bk4, bk5, bk6, bk7, bva0, bva1, bva2, bva3, bvb0, bvb1, bvb2, bvb3;
    u32 br0, br1, br2, br3, bi0, bi1, bi2, bi3;

    int nst = (tt >> 2) + 1;             // 64-wide tiles covering s <= t0+15
    LOADKV64(0, a);
    for (int st = 0; st < nst; st += 2) {
      if (st + 1 < nst) {
        LOADKV64((st + 1) * 64, b);
        WAIT24();
      } else {
        WAIT0();
      }
      COMPUTE64(st * 64, a);
      if (st + 1 < nst) {
        if (st + 2 < nst) {
          LOADKV64((st + 2) * 64, a);
          WAIT24();
        } else {
          WAIT0();
        }
        COMPUTE64((st + 1) * 64, b);
      }
    }

    // ---- per-strip epilogue ----
    float v = lsum;
    v += __shfl_xor(v, 16);
    v += __shfl_xor(v, 32);
    float inv = 1.f / v;

    asm volatile("s_waitcnt lgkmcnt(0)" ::: "memory");
    __builtin_amdgcn_sched_barrier(0);
#pragma unroll
    for (int kc = 0; kc < 2; ++kc) {
      f32x4 pA = *(const f32x4*)&prel[lr * 68 + kc * 32 + sl * 8];
      f32x4 pB = *(const f32x4*)&prel[lr * 68 + kc * 32 + sl * 8 + 4];
      u16 pb[8];
#pragma unroll
      for (int jj = 0; jj < 4; ++jj) { bf16 xx = (bf16)pA[jj]; pb[jj] = *(u16*)&xx; }
#pragma unroll
      for (int jj = 0; jj < 4; ++jj) { bf16 xx = (bf16)pB[jj]; pb[4 + jj] = *(u16*)&xx; }
      bf16x8 pfrag = *(bf16x8*)&pb[0];
#pragma unroll
      for (int ni = 0; ni < 4; ++ni) {
        bf16x8 af = *(const bf16x8*)(rvT + (size_t)(ni * 16 + lr) * 64 + kc * 32 + sl * 8);
        acc[ni] = __builtin_amdgcn_mfma_f32_16x16x32_bf16(af, pfrag, acc[ni], 0, 0, 0);
      }
    }

    bf16* rp = ret + ((size_t)(b * T_ + t0 + lr)) * NX_ + h * HD_ + sl * 4;
#pragma unroll
    for (int ni = 0; ni < 4; ++ni) {
      ushort4v ov;
#pragma unroll
      for (int r = 0; r < 4; ++r) {
        bf16 xx = (bf16)(acc[ni][r] * inv);
        ov[r] = *(u16*)&xx;
      }
      *(ushort4v*)(rp + ni * 16) = ov;
    }
    asm volatile("s_waitcnt lgkmcnt(0)" ::: "memory");
  }
}

extern "C" void kernel_launch(void* const* d_in, const int* in_sizes, int n_in,
                              void* d_out, int out_size, void* d_ws, size_t ws_size,
                              hipStream_t stream) {
  const float* x = (const float*)d_in[0];
  const int* rel = (const int*)d_in[1];
  const float* w_attn = (const float*)d_in[2];
  const float* b_attn = (const float*)d_in[3];
  const float* w_proj = (const float*)d_in[4];
  const float* b_proj = (const float*)d_in[5];
  const float* rel_weights = (const float*)d_in[6];
  const float* rel_values = (const float*)d_in[7];
  const int* rel_ids = (const int*)d_in[8];
  float* out = (float*)d_out;

  char* ws = (char*)d_ws;
  bf16* xb  = (bf16*)(ws);                    //  8 MB: x as bf16 (consumed by gemm<0>)
  bf16* wTa = (bf16*)(ws + 8388608);          //  6 MB: w_attn^T
  bf16* wTp = (bf16*)(ws + 14680064);         //  2 MB: w_proj^T
  bf16* qg  = (bf16*)(ws + 16777216);         //  8 MB: q (bh,t,d)
  bf16* kg  = (bf16*)(ws + 25165824);         //  8 MB: k (bh,t,d)
  bf16* vtg = (bf16*)(ws + 33554432);         //  8 MB: v^T (bh,d,t)
  bf16* ret = (bf16*)(ws + 41943040);         //  8 MB: attn out (b,t,nx)
  // overlays on dead xb region (after gemm<0> consumed it):
  u8* rel8   = (u8*)(ws);                     //  4 MB: rel ids u8 [b][t][s]
  u8* relid8 = (u8*)(ws + 4194304);           //  1 MB: rel_ids u8 [t][s]
  bf16* rvT  = (bf16*)(ws + 5242880);         //  8 KB: rel_values^T bf16 (64d x 64rr)

  k_cvt<<<4096, 256, 0, stream>>>(x, xb, 4194304);
  k_transpose<<<dim3(48, 16), 256, 0, stream>>>(w_attn, wTa, 1024, 3072);
  k_transpose<<<dim3(16, 16), 256, 0, stream>>>(w_proj, wTp, 1024, 1024);
  k_gemm<0><<<dim3(24, 32), 256, 0, stream>>>(xb, wTa, b_attn, nullptr, qg, kg, vtg, 4096, 3072, 1024);
  k_pack<<<5120, 256, 0, stream>>>(rel, rel_ids, rel8);
  k_rvt<<<1, 256, 0, stream>>>(rel_values, rvT);
  k_attn<<<512, 256, 0, stream>>>(qg, kg, vtg, rel8, rel_weights, relid8, rvT, ret);
  k_gemm<1><<<dim3(8, 32), 256, 0, stream>>>(ret, wTp, b_proj, out, nullptr, nullptr, nullptr, 4096, 1024, 1024);
}